// Round 1
// baseline (1033.122 us; speedup 1.0000x reference)
//
#include <hip/hip_runtime.h>
#include <math.h>

#define NN 100000
#define EE 1600000
#define FIN 128
#define DD 64
#define NG 64

// ---- ordered-float <-> uint mapping for atomicMax on floats ----
__device__ __forceinline__ unsigned f2ord(float f) {
  unsigned u = __float_as_uint(f);
  return (u & 0x80000000u) ? ~u : (u | 0x80000000u);
}
__device__ __forceinline__ float ord2f(unsigned m) {
  unsigned u = (m & 0x80000000u) ? (m & 0x7FFFFFFFu) : ~m;
  return __uint_as_float(u);
}

// ---- degree count (col includes implicit self loop handled later) ----
__global__ void count_deg(const int* __restrict__ col, int* __restrict__ deg, int e) {
  int i = blockIdx.x * 256 + threadIdx.x;
  if (i < e) atomicAdd(&deg[col[i]], 1);
}

// in-place: buffer holds int counts, becomes float dinv = (deg+1)^-1/2
__global__ void deg_to_dinv(float* __restrict__ dinv, int n) {
  int i = blockIdx.x * 256 + threadIdx.x;
  if (i < n) {
    int d = __float_as_int(dinv[i]);
    dinv[i] = rsqrtf((float)d + 1.0f);
  }
}

// g1 = glob_init @ w + b   (64 threads)
__global__ void glob1_kernel(const float* __restrict__ gi, const float* __restrict__ w,
                             const float* __restrict__ b, float* __restrict__ out) {
  int j = threadIdx.x;
  float acc = b[j];
  for (int k = 0; k < 64; ++k) acc += gi[k] * w[k * 64 + j];
  out[j] = acc;
}

// h1 = x @ w_nn1 + b_nn1 + g1(broadcast)   [N,128]@[128,64]
__global__ __launch_bounds__(256) void gemm1(const float* __restrict__ x,
    const float* __restrict__ w, const float* __restrict__ b,
    const float* __restrict__ g1, float* __restrict__ h, int n) {
  __shared__ float Ws[FIN][DD];   // 32 KB
  __shared__ float Xs[64][FIN];   // 32 KB
  int base = blockIdx.x * 64;
  for (int idx = threadIdx.x; idx < FIN * DD; idx += 256)
    Ws[idx >> 6][idx & 63] = w[idx];
  for (int idx = threadIdx.x; idx < 64 * FIN; idx += 256) {
    int r = idx >> 7, k = idx & 127;
    int gr = base + r;
    Xs[r][k] = (gr < n) ? x[gr * FIN + k] : 0.f;
  }
  __syncthreads();
  int j = threadIdx.x & 63;
  int rq = threadIdx.x >> 6;
  float bias = b[j] + g1[j];
  for (int rr = 0; rr < 16; ++rr) {
    int r = rq * 16 + rr;
    int gr = base + r;
    float acc = bias;
    #pragma unroll 8
    for (int k = 0; k < FIN; ++k) acc += Xs[r][k] * Ws[k][j];
    if (gr < n) h[gr * DD + j] = acc;
  }
}

// h2 = relu(hin) @ w_nn2 + b_nn2 + globs2[graph_id]   [N,64]@[64,64]
__global__ __launch_bounds__(256) void gemm2(const float* __restrict__ hin,
    const float* __restrict__ w, const float* __restrict__ b,
    const float* __restrict__ globs2, const int* __restrict__ gidx,
    float* __restrict__ h, int n) {
  __shared__ float Ws[DD][DD];   // 16 KB
  __shared__ float Xs[64][DD];   // 16 KB
  int base = blockIdx.x * 64;
  for (int idx = threadIdx.x; idx < DD * DD; idx += 256)
    Ws[idx >> 6][idx & 63] = w[idx];
  for (int idx = threadIdx.x; idx < 64 * DD; idx += 256) {
    int r = idx >> 6, k = idx & 63;
    int gr = base + r;
    Xs[r][k] = (gr < n) ? fmaxf(hin[gr * DD + k], 0.f) : 0.f;
  }
  __syncthreads();
  int j = threadIdx.x & 63;
  int rq = threadIdx.x >> 6;
  for (int rr = 0; rr < 16; ++rr) {
    int r = rq * 16 + rr;
    int gr = base + r;
    if (gr >= n) break;                       // wave-uniform (r is per-wave)
    float acc = b[j] + globs2[gidx[gr] * DD + j];
    #pragma unroll 8
    for (int k = 0; k < DD; ++k) acc += Xs[r][k] * Ws[k][j];
    h[gr * DD + j] = acc;
  }
}

// agg[i] = dinv[i]^2 * h[i]  (self-loop term, also initializes the buffer)
__global__ void init_agg(const float* __restrict__ dinv, const float4* __restrict__ h,
                         float4* __restrict__ agg, int n16) {
  int idx = blockIdx.x * 256 + threadIdx.x;
  if (idx < n16) {
    float d = dinv[idx >> 4];
    float s = d * d;
    float4 v = h[idx];
    v.x *= s; v.y *= s; v.z *= s; v.w *= s;
    agg[idx] = v;
  }
}

// one wave per edge: lane f handles feature f
__global__ __launch_bounds__(256) void edge_scatter(const int* __restrict__ row,
    const int* __restrict__ col, const float* __restrict__ dinv,
    const float* __restrict__ h, float* __restrict__ agg, int e_total) {
  int e = blockIdx.x * 4 + (threadIdx.x >> 6);
  if (e >= e_total) return;
  int f = threadIdx.x & 63;
  int r = row[e], c = col[e];
  float w = dinv[r] * dinv[c];
  atomicAdd(&agg[c * DD + f], w * h[r * DD + f]);
}

// chunked segment-max over sorted graph_indices; block = 64 threads (one per feature)
__global__ void seg_max(const float* __restrict__ B, const int* __restrict__ gidx,
                        unsigned* __restrict__ parts_ord, int n, int chunk) {
  int f = threadIdx.x;
  int start = blockIdx.x * chunk;
  int end = start + chunk; if (end > n) end = n;
  if (start >= end) return;
  int curg = gidx[start];
  float m = -INFINITY;
  for (int i = start; i < end; ++i) {
    int g = gidx[i];
    if (g != curg) {
      atomicMax(&parts_ord[curg * 64 + f], f2ord(m));
      curg = g; m = -INFINITY;
    }
    m = fmaxf(m, B[i * DD + f]);
  }
  atomicMax(&parts_ord[curg * 64 + f], f2ord(m));
}

// globs2[g] = ((glob_init@w_gg1 + b_gg1 + parts[g]@w_ng1 + b_ng1) @ w_gn2 + b_gn2)
__global__ void glob2_kernel(const float* __restrict__ gi, const unsigned* __restrict__ parts_ord,
    const float* __restrict__ w_gg1, const float* __restrict__ b_gg1,
    const float* __restrict__ w_ng1, const float* __restrict__ b_ng1,
    const float* __restrict__ w_gn2, const float* __restrict__ b_gn2,
    float* __restrict__ globs2) {
  __shared__ float t[64];
  int g = blockIdx.x, j = threadIdx.x;
  float acc = b_gg1[j] + b_ng1[j];
  for (int k = 0; k < 64; ++k) acc += gi[k] * w_gg1[k * 64 + j];
  for (int k = 0; k < 64; ++k) acc += ord2f(parts_ord[g * 64 + k]) * w_ng1[k * 64 + j];
  t[j] = acc;
  __syncthreads();
  float acc2 = b_gn2[j];
  for (int k = 0; k < 64; ++k) acc2 += t[k] * w_gn2[k * 64 + j];
  globs2[g * 64 + j] = acc2;
}

__global__ void sigmoid_k(float4* __restrict__ io, int n16) {
  int idx = blockIdx.x * 256 + threadIdx.x;
  if (idx < n16) {
    float4 v = io[idx];
    v.x = 1.f / (1.f + __expf(-v.x));
    v.y = 1.f / (1.f + __expf(-v.y));
    v.z = 1.f / (1.f + __expf(-v.z));
    v.w = 1.f / (1.f + __expf(-v.w));
    io[idx] = v;
  }
}

extern "C" void kernel_launch(void* const* d_in, const int* in_sizes, int n_in,
                              void* d_out, int out_size, void* d_ws, size_t ws_size,
                              hipStream_t stream) {
  const float* x         = (const float*)d_in[0];
  const int*   ei        = (const int*)d_in[1];
  const int*   gidx      = (const int*)d_in[2];
  const float* glob_init = (const float*)d_in[3];
  const float* w_nn1 = (const float*)d_in[4];  const float* b_nn1 = (const float*)d_in[5];
  const float* w_gn1 = (const float*)d_in[6];  const float* b_gn1 = (const float*)d_in[7];
  const float* w_gg1 = (const float*)d_in[8];  const float* b_gg1 = (const float*)d_in[9];
  const float* w_ng1 = (const float*)d_in[10]; const float* b_ng1 = (const float*)d_in[11];
  const float* w_nn2 = (const float*)d_in[12]; const float* b_nn2 = (const float*)d_in[13];
  const float* w_gn2 = (const float*)d_in[14]; const float* b_gn2 = (const float*)d_in[15];
  // w_gg2/b_gg2/w_ng2/b_ng2 (d_in[16..19]) are dead: layer-2 glob output is discarded.

  const int* row = ei;           // edge_index[0]
  const int* col = ei + EE;      // edge_index[1]

  // ---- workspace layout (bytes, 256-aligned) ----
  char* ws = (char*)d_ws;
  float*    dinv    = (float*)ws;                         // N floats (first holds int deg)
  char*     p       = ws + ((NN * 4 + 255) & ~255);
  float*    A       = (float*)p;                          // h buffer, N*64 f32
  p += (size_t)NN * DD * 4;
  unsigned* parts   = (unsigned*)p;  p += NG * 64 * 4;    // ordered-max accumulators
  float*    g1      = (float*)p;     p += 256;            // 64 floats
  float*    globs2  = (float*)p;                          // NG*64 floats
  float*    out     = (float*)d_out;                      // doubles as agg buffer

  const int n16 = NN * DD / 4;

  // degree -> dinv (shared by both layers)
  hipMemsetAsync(dinv, 0, NN * 4, stream);
  count_deg<<<(EE + 255) / 256, 256, 0, stream>>>(col, (int*)dinv, EE);
  deg_to_dinv<<<(NN + 255) / 256, 256, 0, stream>>>(dinv, NN);

  // ---- layer 1 ----
  glob1_kernel<<<1, 64, 0, stream>>>(glob_init, w_gn1, b_gn1, g1);
  gemm1<<<(NN + 63) / 64, 256, 0, stream>>>(x, w_nn1, b_nn1, g1, A, NN);
  init_agg<<<(n16 + 255) / 256, 256, 0, stream>>>(dinv, (const float4*)A, (float4*)out, n16);
  edge_scatter<<<(EE + 3) / 4, 256, 0, stream>>>(row, col, dinv, A, out, EE);

  // readout -> per-graph globals for layer 2
  hipMemsetAsync(parts, 0, NG * 64 * 4, stream);
  seg_max<<<(NN + 127) / 128, 64, 0, stream>>>(out, gidx, parts, NN, 128);
  glob2_kernel<<<NG, 64, 0, stream>>>(glob_init, parts, w_gg1, b_gg1, w_ng1, b_ng1,
                                      w_gn2, b_gn2, globs2);

  // ---- layer 2 (glob output discarded by reference) ----
  gemm2<<<(NN + 63) / 64, 256, 0, stream>>>(out, w_nn2, b_nn2, globs2, gidx, A, NN);
  init_agg<<<(n16 + 255) / 256, 256, 0, stream>>>(dinv, (const float4*)A, (float4*)out, n16);
  edge_scatter<<<(EE + 3) / 4, 256, 0, stream>>>(row, col, dinv, A, out, EE);
  sigmoid_k<<<(n16 + 255) / 256, 256, 0, stream>>>((float4*)out, n16);
}

// Round 2
// 594.877 us; speedup vs baseline: 1.7367x; 1.7367x over previous
//
#include <hip/hip_runtime.h>
#include <math.h>

#define NN 100000
#define EE 1600000
#define FIN 128
#define DD 64
#define NG 64

// ---- ordered-float <-> uint mapping for atomicMax on floats ----
__device__ __forceinline__ unsigned f2ord(float f) {
  unsigned u = __float_as_uint(f);
  return (u & 0x80000000u) ? ~u : (u | 0x80000000u);
}
__device__ __forceinline__ float ord2f(unsigned m) {
  unsigned u = (m & 0x80000000u) ? (m & 0x7FFFFFFFu) : ~m;
  return __uint_as_float(u);
}

// ---- degree count over col (self loops added analytically later) ----
__global__ void count_deg(const int* __restrict__ col, int* __restrict__ deg, int e) {
  int i = blockIdx.x * 256 + threadIdx.x;
  if (i < e) atomicAdd(&deg[col[i]], 1);
}

__global__ void deg_to_dinv(const int* __restrict__ deg, float* __restrict__ dinv, int n) {
  int i = blockIdx.x * 256 + threadIdx.x;
  if (i < n) dinv[i] = rsqrtf((float)deg[i] + 1.0f);   // +1 = self loop
}

// ---- 3-kernel exclusive scan of deg -> cursor (CSC bucket starts) ----
__global__ __launch_bounds__(1024) void scan1(const int* __restrict__ deg,
    int* __restrict__ cur, int* __restrict__ bsum, int n) {
  __shared__ int s[1024];
  int tid = threadIdx.x;
  int i = blockIdx.x * 1024 + tid;
  int v = (i < n) ? deg[i] : 0;
  s[tid] = v;
  __syncthreads();
  for (int off = 1; off < 1024; off <<= 1) {
    int t = (tid >= off) ? s[tid - off] : 0;
    __syncthreads();
    s[tid] += t;
    __syncthreads();
  }
  if (i < n) cur[i] = s[tid] - v;          // exclusive within block
  if (tid == 1023) bsum[blockIdx.x] = s[1023];
}

__global__ void scan2(int* __restrict__ bsum, int nb) {
  if (threadIdx.x == 0 && blockIdx.x == 0) {
    int acc = 0;
    for (int b = 0; b < nb; ++b) { int t = bsum[b]; bsum[b] = acc; acc += t; }
  }
}

__global__ void scan3(int* __restrict__ cur, const int* __restrict__ bsum, int n) {
  int i = blockIdx.x * 256 + threadIdx.x;
  if (i < n) cur[i] += bsum[i >> 10];
}

// ---- bucket edges by destination; pack (src, norm-weight) into 8 B ----
__global__ void reorder(const int* __restrict__ row, const int* __restrict__ col,
                        const float* __restrict__ dinv, int* __restrict__ cursor,
                        int2* __restrict__ csr, int e) {
  int i = blockIdx.x * 256 + threadIdx.x;
  if (i < e) {
    int r = row[i], c = col[i];
    int pos = atomicAdd(&cursor[c], 1);
    csr[pos] = make_int2(r, __float_as_int(dinv[r] * dinv[c]));
  }
}

// g1 = glob_init @ w + b   (64 threads)
__global__ void glob1_kernel(const float* __restrict__ gi, const float* __restrict__ w,
                             const float* __restrict__ b, float* __restrict__ out) {
  int j = threadIdx.x;
  float acc = b[j];
  for (int k = 0; k < 64; ++k) acc += gi[k] * w[k * 64 + j];
  out[j] = acc;
}

// h1 = x @ w_nn1 + b_nn1 + g1(broadcast)   [N,128]@[128,64]
__global__ __launch_bounds__(256) void gemm1(const float* __restrict__ x,
    const float* __restrict__ w, const float* __restrict__ b,
    const float* __restrict__ g1, float* __restrict__ h, int n) {
  __shared__ float Ws[FIN][DD];   // 32 KB
  __shared__ float Xs[64][FIN];   // 32 KB
  int base = blockIdx.x * 64;
  for (int idx = threadIdx.x; idx < FIN * DD; idx += 256)
    Ws[idx >> 6][idx & 63] = w[idx];
  for (int idx = threadIdx.x; idx < 64 * FIN; idx += 256) {
    int r = idx >> 7, k = idx & 127;
    int gr = base + r;
    Xs[r][k] = (gr < n) ? x[gr * FIN + k] : 0.f;
  }
  __syncthreads();
  int j = threadIdx.x & 63;
  int rq = threadIdx.x >> 6;
  float bias = b[j] + g1[j];
  for (int rr = 0; rr < 16; ++rr) {
    int r = rq * 16 + rr;
    int gr = base + r;
    float acc = bias;
    #pragma unroll 8
    for (int k = 0; k < FIN; ++k) acc += Xs[r][k] * Ws[k][j];
    if (gr < n) h[gr * DD + j] = acc;
  }
}

// h2 = relu(hin) @ w_nn2 + b_nn2 + globs2[graph_id]   [N,64]@[64,64]
__global__ __launch_bounds__(256) void gemm2(const float* __restrict__ hin,
    const float* __restrict__ w, const float* __restrict__ b,
    const float* __restrict__ globs2, const int* __restrict__ gidx,
    float* __restrict__ h, int n) {
  __shared__ float Ws[DD][DD];   // 16 KB
  __shared__ float Xs[64][DD];   // 16 KB
  int base = blockIdx.x * 64;
  for (int idx = threadIdx.x; idx < DD * DD; idx += 256)
    Ws[idx >> 6][idx & 63] = w[idx];
  for (int idx = threadIdx.x; idx < 64 * DD; idx += 256) {
    int r = idx >> 6, k = idx & 63;
    int gr = base + r;
    Xs[r][k] = (gr < n) ? fmaxf(hin[gr * DD + k], 0.f) : 0.f;
  }
  __syncthreads();
  int j = threadIdx.x & 63;
  int rq = threadIdx.x >> 6;
  for (int rr = 0; rr < 16; ++rr) {
    int r = rq * 16 + rr;
    int gr = base + r;
    if (gr >= n) break;                       // wave-uniform (r is per-wave)
    float acc = b[j] + globs2[gidx[gr] * DD + j];
    #pragma unroll 8
    for (int k = 0; k < DD; ++k) acc += Xs[r][k] * Ws[k][j];
    h[gr * DD + j] = acc;
  }
}

// ---- pull-gather aggregation: one wave per node, lane = feature ----
// out[c] = dinv[c]^2 * h[c] + sum_e w_e * h[src_e];  optional sigmoid
template <int SIG>
__global__ __launch_bounds__(256) void gather_agg(const int2* __restrict__ csr,
    const int* __restrict__ cursor, const int* __restrict__ deg,
    const float* __restrict__ dinv, const float* __restrict__ h,
    float* __restrict__ out, int n) {
  int node = blockIdx.x * 4 + (threadIdx.x >> 6);
  if (node >= n) return;
  int f = threadIdx.x & 63;
  int end = cursor[node];             // cursor was advanced to bucket end by reorder
  int start = end - deg[node];
  float di = dinv[node];
  float acc = di * di * h[node * DD + f];
  int e = start;
  for (; e + 1 < end; e += 2) {
    int2 r0 = csr[e];
    int2 r1 = csr[e + 1];
    float v0 = h[r0.x * DD + f];
    float v1 = h[r1.x * DD + f];
    acc += __int_as_float(r0.y) * v0;
    acc += __int_as_float(r1.y) * v1;
  }
  if (e < end) {
    int2 r0 = csr[e];
    acc += __int_as_float(r0.y) * h[r0.x * DD + f];
  }
  if (SIG) acc = 1.f / (1.f + __expf(-acc));
  out[node * DD + f] = acc;
}

// chunked segment-max over sorted graph_indices; block = 64 threads (one per feature)
__global__ void seg_max(const float* __restrict__ B, const int* __restrict__ gidx,
                        unsigned* __restrict__ parts_ord, int n, int chunk) {
  int f = threadIdx.x;
  int start = blockIdx.x * chunk;
  int end = start + chunk; if (end > n) end = n;
  if (start >= end) return;
  int curg = gidx[start];
  float m = -INFINITY;
  for (int i = start; i < end; ++i) {
    int g = gidx[i];
    if (g != curg) {
      atomicMax(&parts_ord[curg * 64 + f], f2ord(m));
      curg = g; m = -INFINITY;
    }
    m = fmaxf(m, B[i * DD + f]);
  }
  atomicMax(&parts_ord[curg * 64 + f], f2ord(m));
}

// globs2[g] = ((glob_init@w_gg1 + b_gg1 + parts[g]@w_ng1 + b_ng1) @ w_gn2 + b_gn2)
__global__ void glob2_kernel(const float* __restrict__ gi, const unsigned* __restrict__ parts_ord,
    const float* __restrict__ w_gg1, const float* __restrict__ b_gg1,
    const float* __restrict__ w_ng1, const float* __restrict__ b_ng1,
    const float* __restrict__ w_gn2, const float* __restrict__ b_gn2,
    float* __restrict__ globs2) {
  __shared__ float t[64];
  int g = blockIdx.x, j = threadIdx.x;
  float acc = b_gg1[j] + b_ng1[j];
  for (int k = 0; k < 64; ++k) acc += gi[k] * w_gg1[k * 64 + j];
  for (int k = 0; k < 64; ++k) acc += ord2f(parts_ord[g * 64 + k]) * w_ng1[k * 64 + j];
  t[j] = acc;
  __syncthreads();
  float acc2 = b_gn2[j];
  for (int k = 0; k < 64; ++k) acc2 += t[k] * w_gn2[k * 64 + j];
  globs2[g * 64 + j] = acc2;
}

extern "C" void kernel_launch(void* const* d_in, const int* in_sizes, int n_in,
                              void* d_out, int out_size, void* d_ws, size_t ws_size,
                              hipStream_t stream) {
  const float* x         = (const float*)d_in[0];
  const int*   ei        = (const int*)d_in[1];
  const int*   gidx      = (const int*)d_in[2];
  const float* glob_init = (const float*)d_in[3];
  const float* w_nn1 = (const float*)d_in[4];  const float* b_nn1 = (const float*)d_in[5];
  const float* w_gn1 = (const float*)d_in[6];  const float* b_gn1 = (const float*)d_in[7];
  const float* w_gg1 = (const float*)d_in[8];  const float* b_gg1 = (const float*)d_in[9];
  const float* w_ng1 = (const float*)d_in[10]; const float* b_ng1 = (const float*)d_in[11];
  const float* w_nn2 = (const float*)d_in[12]; const float* b_nn2 = (const float*)d_in[13];
  const float* w_gn2 = (const float*)d_in[14]; const float* b_gn2 = (const float*)d_in[15];
  // w_gg2/b_gg2/w_ng2/b_ng2 are dead: layer-2 glob output is discarded.

  const int* row = ei;           // edge_index[0]
  const int* col = ei + EE;      // edge_index[1]

  // ---- workspace layout (256-aligned) ----
  char* p = (char*)d_ws;
  int*      deg    = (int*)p;       p += ((NN * 4 + 255) & ~255);
  float*    dinv   = (float*)p;     p += ((NN * 4 + 255) & ~255);
  int*      cursor = (int*)p;       p += ((NN * 4 + 255) & ~255);
  int*      bsum   = (int*)p;       p += 1024;
  int2*     csr    = (int2*)p;      p += (size_t)EE * 8;
  float*    A      = (float*)p;     p += (size_t)NN * DD * 4;
  unsigned* parts  = (unsigned*)p;  p += NG * 64 * 4;
  float*    g1     = (float*)p;     p += 256;
  float*    globs2 = (float*)p;
  float*    out    = (float*)d_out;            // doubles as agg1 buffer

  const int NB = (NN + 1023) / 1024;           // scan blocks

  // ---- CSC build (shared by both layers) ----
  hipMemsetAsync(deg, 0, NN * 4, stream);
  count_deg<<<(EE + 255) / 256, 256, 0, stream>>>(col, deg, EE);
  deg_to_dinv<<<(NN + 255) / 256, 256, 0, stream>>>(deg, dinv, NN);
  scan1<<<NB, 1024, 0, stream>>>(deg, cursor, bsum, NN);
  scan2<<<1, 64, 0, stream>>>(bsum, NB);
  scan3<<<(NN + 255) / 256, 256, 0, stream>>>(cursor, bsum, NN);
  reorder<<<(EE + 255) / 256, 256, 0, stream>>>(row, col, dinv, cursor, csr, EE);

  // ---- layer 1 ----
  glob1_kernel<<<1, 64, 0, stream>>>(glob_init, w_gn1, b_gn1, g1);
  gemm1<<<(NN + 63) / 64, 256, 0, stream>>>(x, w_nn1, b_nn1, g1, A, NN);
  gather_agg<0><<<(NN + 3) / 4, 256, 0, stream>>>(csr, cursor, deg, dinv, A, out, NN);

  // readout -> per-graph globals for layer 2
  hipMemsetAsync(parts, 0, NG * 64 * 4, stream);
  seg_max<<<(NN + 63) / 64, 64, 0, stream>>>(out, gidx, parts, NN, 64);
  glob2_kernel<<<NG, 64, 0, stream>>>(glob_init, parts, w_gg1, b_gg1, w_ng1, b_ng1,
                                      w_gn2, b_gn2, globs2);

  // ---- layer 2 (glob output discarded by reference) ----
  gemm2<<<(NN + 63) / 64, 256, 0, stream>>>(out, w_nn2, b_nn2, globs2, gidx, A, NN);
  gather_agg<1><<<(NN + 3) / 4, 256, 0, stream>>>(csr, cursor, deg, dinv, A, out, NN);
}

// Round 3
// 400.214 us; speedup vs baseline: 2.5814x; 1.4864x over previous
//
#include <hip/hip_runtime.h>
#include <math.h>

#define NN 100000
#define EE 1600000
#define FIN 128
#define DD 64
#define NG 64

typedef unsigned int uint;
typedef unsigned short ushort;

// ---- ordered-float <-> uint mapping for atomicMax on floats ----
__device__ __forceinline__ unsigned f2ord(float f) {
  unsigned u = __float_as_uint(f);
  return (u & 0x80000000u) ? ~u : (u | 0x80000000u);
}
__device__ __forceinline__ float ord2f(unsigned m) {
  unsigned u = (m & 0x80000000u) ? (m & 0x7FFFFFFFu) : ~m;
  return __uint_as_float(u);
}
// ---- bf16 helpers (fp32 accumulate everywhere; RNE pack) ----
__device__ __forceinline__ float bflo(uint v) { return __uint_as_float(v << 16); }
__device__ __forceinline__ float bfhi(uint v) { return __uint_as_float(v & 0xffff0000u); }
__device__ __forceinline__ uint bfr(float x) {
  uint u = __float_as_uint(x);
  return (u + 0x7fffu + ((u >> 16) & 1u)) >> 16;
}
__device__ __forceinline__ uint packbf(float lo, float hi) { return bfr(lo) | (bfr(hi) << 16); }

// ---- degree count over col (self loops added analytically: deg+1) ----
__global__ void count_deg(const int* __restrict__ col, int* __restrict__ deg, int e) {
  int i = blockIdx.x * 256 + threadIdx.x;
  if (i < e) atomicAdd(&deg[col[i]], 1);
}

__global__ void deg_to_dinv(const int* __restrict__ deg, float* __restrict__ dinv, int n) {
  int i = blockIdx.x * 256 + threadIdx.x;
  if (i < n) dinv[i] = rsqrtf((float)deg[i] + 1.0f);
}

// ---- 3-kernel exclusive scan of deg -> cursor (CSC bucket starts) ----
__global__ __launch_bounds__(1024) void scan1(const int* __restrict__ deg,
    int* __restrict__ cur, int* __restrict__ bsum, int n) {
  __shared__ int s[1024];
  int tid = threadIdx.x;
  int i = blockIdx.x * 1024 + tid;
  int v = (i < n) ? deg[i] : 0;
  s[tid] = v;
  __syncthreads();
  for (int off = 1; off < 1024; off <<= 1) {
    int t = (tid >= off) ? s[tid - off] : 0;
    __syncthreads();
    s[tid] += t;
    __syncthreads();
  }
  if (i < n) cur[i] = s[tid] - v;
  if (tid == 1023) bsum[blockIdx.x] = s[1023];
}

__global__ void scan2(int* __restrict__ bsum, int nb) {
  if (threadIdx.x == 0 && blockIdx.x == 0) {
    int acc = 0;
    for (int b = 0; b < nb; ++b) { int t = bsum[b]; bsum[b] = acc; acc += t; }
  }
}

__global__ void scan3(int* __restrict__ cur, const int* __restrict__ bsum, int n) {
  int i = blockIdx.x * 256 + threadIdx.x;
  if (i < n) cur[i] += bsum[i >> 10];
}

// ---- bucket edges by destination; pack (src, norm-weight) into 8 B ----
__global__ void reorder(const int* __restrict__ row, const int* __restrict__ col,
                        const float* __restrict__ dinv, int* __restrict__ cursor,
                        int2* __restrict__ csr, int e) {
  int i = blockIdx.x * 256 + threadIdx.x;
  if (i < e) {
    int r = row[i], c = col[i];
    int pos = atomicAdd(&cursor[c], 1);
    csr[pos] = make_int2(r, __float_as_int(dinv[r] * dinv[c]));
  }
}

// g1 = glob_init @ w + b   (64 threads)
__global__ void glob1_kernel(const float* __restrict__ gi, const float* __restrict__ w,
                             const float* __restrict__ b, float* __restrict__ out) {
  int j = threadIdx.x;
  float acc = b[j];
  for (int k = 0; k < 64; ++k) acc += gi[k] * w[k * 64 + j];
  out[j] = acc;
}

// ---- gemm1: h1 = x @ w_nn1 + b_nn1 + g1, output bf16-packed [N][32] uints ----
// 64x64 tile, 256 threads, 4x4 accs/thread; A staged transposed with XOR swizzle
// col' = r ^ (k & 60) so both fragment reads are ds_read_b128 and conflict-light.
__global__ __launch_bounds__(256) void gemm1(const float* __restrict__ x,
    const float* __restrict__ w, const float* __restrict__ b,
    const float* __restrict__ g1, uint* __restrict__ hbf, int n) {
  __shared__ float XsT[FIN][64];   // [k][r^swz] 32 KB
  __shared__ float Ws[FIN][DD];    // [k][j]     32 KB
  int base = blockIdx.x * 64;
  const float4* w4 = (const float4*)w;
  float4* ws4 = (float4*)Ws;
  for (int idx = threadIdx.x; idx < FIN * DD / 4; idx += 256) ws4[idx] = w4[idx];
  const float4* x4 = (const float4*)x;
  for (int idx = threadIdx.x; idx < 64 * FIN / 4; idx += 256) {
    int kq = idx & 31, r = idx >> 5;          // coalesced: 32 lanes span one 512B row
    int gr = base + r;
    float4 v = make_float4(0.f, 0.f, 0.f, 0.f);
    if (gr < n) v = x4[gr * 32 + kq];
    int k0 = kq * 4, s = k0 & 60;
    XsT[k0 + 0][r ^ s] = v.x;
    XsT[k0 + 1][r ^ s] = v.y;
    XsT[k0 + 2][r ^ s] = v.z;
    XsT[k0 + 3][r ^ s] = v.w;
  }
  __syncthreads();
  int tx = threadIdx.x & 15, ty = threadIdx.x >> 4;
  float acc[4][4] = {};
  #pragma unroll 4
  for (int k = 0; k < FIN; ++k) {
    float4 av = *(const float4*)&XsT[k][(4 * ty) ^ (k & 60)];
    float4 bv = *(const float4*)&Ws[k][4 * tx];
    float ax[4] = {av.x, av.y, av.z, av.w};
    float bx[4] = {bv.x, bv.y, bv.z, bv.w};
    #pragma unroll
    for (int i = 0; i < 4; ++i)
      #pragma unroll
      for (int j = 0; j < 4; ++j)
        acc[i][j] += ax[i] * bx[j];
  }
  float bias[4];
  #pragma unroll
  for (int j = 0; j < 4; ++j) bias[j] = b[4 * tx + j] + g1[4 * tx + j];
  #pragma unroll
  for (int i = 0; i < 4; ++i) {
    int row = base + 4 * ty + i;
    if (row < n) {
      hbf[row * 32 + 2 * tx]     = packbf(acc[i][0] + bias[0], acc[i][1] + bias[1]);
      hbf[row * 32 + 2 * tx + 1] = packbf(acc[i][2] + bias[2], acc[i][3] + bias[3]);
    }
  }
}

// ---- gemm2: h2 = relu(hin) @ w_nn2 + b_nn2 + globs2[gidx], bf16 in/out ----
__global__ __launch_bounds__(256) void gemm2(const uint* __restrict__ hbf,
    const float* __restrict__ w, const float* __restrict__ bb,
    const float* __restrict__ globs2, const int* __restrict__ gidx,
    uint* __restrict__ obf, int n) {
  __shared__ float XsT[DD][64];    // 16 KB
  __shared__ float Ws[DD][DD];     // 16 KB
  int base = blockIdx.x * 64;
  const float4* w4 = (const float4*)w;
  float4* ws4 = (float4*)Ws;
  for (int idx = threadIdx.x; idx < DD * DD / 4; idx += 256) ws4[idx] = w4[idx];
  const uint2* h2 = (const uint2*)hbf;
  for (int idx = threadIdx.x; idx < 64 * DD / 4; idx += 256) {
    int kq = idx & 15, r = idx >> 4;
    int gr = base + r;
    uint2 v = make_uint2(0u, 0u);
    if (gr < n) v = h2[gr * 16 + kq];
    int k0 = kq * 4, s = k0 & 60;
    XsT[k0 + 0][r ^ s] = fmaxf(bflo(v.x), 0.f);
    XsT[k0 + 1][r ^ s] = fmaxf(bfhi(v.x), 0.f);
    XsT[k0 + 2][r ^ s] = fmaxf(bflo(v.y), 0.f);
    XsT[k0 + 3][r ^ s] = fmaxf(bfhi(v.y), 0.f);
  }
  __syncthreads();
  int tx = threadIdx.x & 15, ty = threadIdx.x >> 4;
  float acc[4][4] = {};
  #pragma unroll 4
  for (int k = 0; k < DD; ++k) {
    float4 av = *(const float4*)&XsT[k][(4 * ty) ^ (k & 60)];
    float4 bv = *(const float4*)&Ws[k][4 * tx];
    float ax[4] = {av.x, av.y, av.z, av.w};
    float bx[4] = {bv.x, bv.y, bv.z, bv.w};
    #pragma unroll
    for (int i = 0; i < 4; ++i)
      #pragma unroll
      for (int j = 0; j < 4; ++j)
        acc[i][j] += ax[i] * bx[j];
  }
  #pragma unroll
  for (int i = 0; i < 4; ++i) {
    int row = base + 4 * ty + i;
    if (row < n) {
      const float* gl = globs2 + gidx[row] * 64 + 4 * tx;
      float c0 = acc[i][0] + bb[4 * tx + 0] + gl[0];
      float c1 = acc[i][1] + bb[4 * tx + 1] + gl[1];
      float c2 = acc[i][2] + bb[4 * tx + 2] + gl[2];
      float c3 = acc[i][3] + bb[4 * tx + 3] + gl[3];
      obf[row * 32 + 2 * tx]     = packbf(c0, c1);
      obf[row * 32 + 2 * tx + 1] = packbf(c2, c3);
    }
  }
}

// ---- pull-gather: one wave per node, halves process even/odd edges.
// h is bf16-packed [N][32] uints; lane fp handles features 2fp, 2fp+1.
template <int SIG>
__global__ __launch_bounds__(256) void gather_agg(const int2* __restrict__ csr,
    const int* __restrict__ cursor, const int* __restrict__ deg,
    const float* __restrict__ dinv, const uint* __restrict__ h,
    void* __restrict__ outv, int n) {
  int node = blockIdx.x * 4 + (threadIdx.x >> 6);
  if (node >= n) return;
  int lane = threadIdx.x & 63;
  int half = lane >> 5, fp = lane & 31;
  int end = cursor[node];              // reorder advanced cursor to bucket end
  int start = end - deg[node];
  float a0 = 0.f, a1 = 0.f;
  int e = start + half;
  for (; e + 2 < end; e += 4) {        // 2 edges in flight per half
    int2 r0 = csr[e];
    int2 r1 = csr[e + 2];
    uint h0 = h[r0.x * 32 + fp];
    uint h1 = h[r1.x * 32 + fp];
    float w0 = __int_as_float(r0.y), w1 = __int_as_float(r1.y);
    a0 += w0 * bflo(h0) + w1 * bflo(h1);
    a1 += w0 * bfhi(h0) + w1 * bfhi(h1);
  }
  if (e < end) {
    int2 r0 = csr[e];
    uint h0 = h[r0.x * 32 + fp];
    float w0 = __int_as_float(r0.y);
    a0 += w0 * bflo(h0);
    a1 += w0 * bfhi(h0);
  }
  if (half == 0) {                     // self-loop term, counted once
    float di = dinv[node], sc = di * di;
    uint hv = h[node * 32 + fp];
    a0 += sc * bflo(hv);
    a1 += sc * bfhi(hv);
  }
  a0 += __shfl(a0, lane ^ 32);
  a1 += __shfl(a1, lane ^ 32);
  if (half == 0) {
    if (SIG) {
      float2 o;
      o.x = 1.f / (1.f + __expf(-a0));
      o.y = 1.f / (1.f + __expf(-a1));
      ((float2*)outv)[node * 32 + fp] = o;
    } else {
      ((uint*)outv)[node * 32 + fp] = packbf(a0, a1);
    }
  }
}

// chunked segment-max over sorted graph_indices; bf16 input
__global__ void seg_max(const ushort* __restrict__ B, const int* __restrict__ gidx,
                        unsigned* __restrict__ parts_ord, int n, int chunk) {
  int f = threadIdx.x;
  int start = blockIdx.x * chunk;
  int end = start + chunk; if (end > n) end = n;
  if (start >= end) return;
  int curg = gidx[start];
  float m = -INFINITY;
  for (int i = start; i < end; ++i) {
    int g = gidx[i];
    if (g != curg) {
      atomicMax(&parts_ord[curg * 64 + f], f2ord(m));
      curg = g; m = -INFINITY;
    }
    m = fmaxf(m, __uint_as_float(((uint)B[i * 64 + f]) << 16));
  }
  atomicMax(&parts_ord[curg * 64 + f], f2ord(m));
}

// globs2[g] = ((glob_init@w_gg1 + b_gg1 + parts[g]@w_ng1 + b_ng1) @ w_gn2 + b_gn2)
__global__ void glob2_kernel(const float* __restrict__ gi, const unsigned* __restrict__ parts_ord,
    const float* __restrict__ w_gg1, const float* __restrict__ b_gg1,
    const float* __restrict__ w_ng1, const float* __restrict__ b_ng1,
    const float* __restrict__ w_gn2, const float* __restrict__ b_gn2,
    float* __restrict__ globs2) {
  __shared__ float t[64];
  int g = blockIdx.x, j = threadIdx.x;
  float acc = b_gg1[j] + b_ng1[j];
  for (int k = 0; k < 64; ++k) acc += gi[k] * w_gg1[k * 64 + j];
  for (int k = 0; k < 64; ++k) acc += ord2f(parts_ord[g * 64 + k]) * w_ng1[k * 64 + j];
  t[j] = acc;
  __syncthreads();
  float acc2 = b_gn2[j];
  for (int k = 0; k < 64; ++k) acc2 += t[k] * w_gn2[k * 64 + j];
  globs2[g * 64 + j] = acc2;
}

extern "C" void kernel_launch(void* const* d_in, const int* in_sizes, int n_in,
                              void* d_out, int out_size, void* d_ws, size_t ws_size,
                              hipStream_t stream) {
  const float* x         = (const float*)d_in[0];
  const int*   ei        = (const int*)d_in[1];
  const int*   gidx      = (const int*)d_in[2];
  const float* glob_init = (const float*)d_in[3];
  const float* w_nn1 = (const float*)d_in[4];  const float* b_nn1 = (const float*)d_in[5];
  const float* w_gn1 = (const float*)d_in[6];  const float* b_gn1 = (const float*)d_in[7];
  const float* w_gg1 = (const float*)d_in[8];  const float* b_gg1 = (const float*)d_in[9];
  const float* w_ng1 = (const float*)d_in[10]; const float* b_ng1 = (const float*)d_in[11];
  const float* w_nn2 = (const float*)d_in[12]; const float* b_nn2 = (const float*)d_in[13];
  const float* w_gn2 = (const float*)d_in[14]; const float* b_gn2 = (const float*)d_in[15];
  // w_gg2/b_gg2/w_ng2/b_ng2 are dead: layer-2 glob output is discarded.

  const int* row = ei;           // edge_index[0]
  const int* col = ei + EE;      // edge_index[1]

  // ---- workspace layout (256-aligned) ----
  char* p = (char*)d_ws;
  int*      deg    = (int*)p;       p += ((NN * 4 + 255) & ~255);
  float*    dinv   = (float*)p;     p += ((NN * 4 + 255) & ~255);
  int*      cursor = (int*)p;       p += ((NN * 4 + 255) & ~255);
  int*      bsum   = (int*)p;       p += 1024;
  int2*     csr    = (int2*)p;      p += (size_t)EE * 8;
  uint*     A      = (uint*)p;      p += (size_t)NN * 32 * 4;   // bf16 h buffer [N][32] uints
  unsigned* parts  = (unsigned*)p;  p += NG * 64 * 4;
  float*    g1     = (float*)p;     p += 256;
  float*    globs2 = (float*)p;
  uint*     B      = (uint*)d_out;  // bf16 agg1 buffer lives in d_out (fully overwritten later)
  float*    out    = (float*)d_out;

  const int NB = (NN + 1023) / 1024;

  // ---- CSC build (shared by both layers) ----
  hipMemsetAsync(deg, 0, NN * 4, stream);
  count_deg<<<(EE + 255) / 256, 256, 0, stream>>>(col, deg, EE);
  deg_to_dinv<<<(NN + 255) / 256, 256, 0, stream>>>(deg, dinv, NN);
  scan1<<<NB, 1024, 0, stream>>>(deg, cursor, bsum, NN);
  scan2<<<1, 64, 0, stream>>>(bsum, NB);
  scan3<<<(NN + 255) / 256, 256, 0, stream>>>(cursor, bsum, NN);
  reorder<<<(EE + 255) / 256, 256, 0, stream>>>(row, col, dinv, cursor, csr, EE);

  // ---- layer 1 ----
  glob1_kernel<<<1, 64, 0, stream>>>(glob_init, w_gn1, b_gn1, g1);
  gemm1<<<(NN + 63) / 64, 256, 0, stream>>>(x, w_nn1, b_nn1, g1, A, NN);
  gather_agg<0><<<(NN + 3) / 4, 256, 0, stream>>>(csr, cursor, deg, dinv, A, (void*)B, NN);

  // readout -> per-graph globals for layer 2
  hipMemsetAsync(parts, 0, NG * 64 * 4, stream);
  seg_max<<<(NN + 63) / 64, 64, 0, stream>>>((const ushort*)B, gidx, parts, NN, 64);
  glob2_kernel<<<NG, 64, 0, stream>>>(glob_init, parts, w_gg1, b_gg1, w_ng1, b_ng1,
                                      w_gn2, b_gn2, globs2);

  // ---- layer 2 (glob output discarded by reference) ----
  gemm2<<<(NN + 63) / 64, 256, 0, stream>>>(B, w_nn2, b_nn2, globs2, gidx, A, NN);
  gather_agg<1><<<(NN + 3) / 4, 256, 0, stream>>>(csr, cursor, deg, dinv, A, (void*)out, NN);
}

// Round 4
// 374.024 us; speedup vs baseline: 2.7622x; 1.0700x over previous
//
#include <hip/hip_runtime.h>
#include <math.h>

#define NN 100000
#define EE 1600000
#define FIN 128
#define DD 64
#define NG 64
#define NXCD 8
#define RNG ((NN + NXCD - 1) / NXCD)   // 12500 nodes per XCD range
#define EPB 8                          // edges per thread in reorder scan

typedef unsigned int uint;
typedef unsigned short ushort;

// ---- ordered-float <-> uint mapping for atomicMax on floats ----
__device__ __forceinline__ unsigned f2ord(float f) {
  unsigned u = __float_as_uint(f);
  return (u & 0x80000000u) ? ~u : (u | 0x80000000u);
}
__device__ __forceinline__ float ord2f(unsigned m) {
  unsigned u = (m & 0x80000000u) ? (m & 0x7FFFFFFFu) : ~m;
  return __uint_as_float(u);
}
// ---- bf16 helpers (fp32 accumulate everywhere; RNE pack) ----
__device__ __forceinline__ float bflo(uint v) { return __uint_as_float(v << 16); }
__device__ __forceinline__ float bfhi(uint v) { return __uint_as_float(v & 0xffff0000u); }
__device__ __forceinline__ uint bfr(float x) {
  uint u = __float_as_uint(x);
  return (u + 0x7fffu + ((u >> 16) & 1u)) >> 16;
}
__device__ __forceinline__ uint packbf(float lo, float hi) { return bfr(lo) | (bfr(hi) << 16); }

// ---- degree count over col (self loops added analytically: deg+1) ----
__global__ void count_deg(const int* __restrict__ col, int* __restrict__ deg, int e) {
  int i = blockIdx.x * 256 + threadIdx.x;
  if (i < e) atomicAdd(&deg[col[i]], 1);
}

__global__ void deg_to_dinv(const int* __restrict__ deg, float* __restrict__ dinv, int n) {
  int i = blockIdx.x * 256 + threadIdx.x;
  if (i < n) dinv[i] = rsqrtf((float)deg[i] + 1.0f);
}

// ---- 3-kernel exclusive scan of deg -> cursor (CSC bucket starts) ----
__global__ __launch_bounds__(1024) void scan1(const int* __restrict__ deg,
    int* __restrict__ cur, int* __restrict__ bsum, int n) {
  __shared__ int s[1024];
  int tid = threadIdx.x;
  int i = blockIdx.x * 1024 + tid;
  int v = (i < n) ? deg[i] : 0;
  s[tid] = v;
  __syncthreads();
  for (int off = 1; off < 1024; off <<= 1) {
    int t = (tid >= off) ? s[tid - off] : 0;
    __syncthreads();
    s[tid] += t;
    __syncthreads();
  }
  if (i < n) cur[i] = s[tid] - v;
  if (tid == 1023) bsum[blockIdx.x] = s[1023];
}

__global__ void scan2(int* __restrict__ bsum, int nb) {
  if (threadIdx.x == 0 && blockIdx.x == 0) {
    int acc = 0;
    for (int b = 0; b < nb; ++b) { int t = bsum[b]; bsum[b] = acc; acc += t; }
  }
}

__global__ void scan3(int* __restrict__ cur, const int* __restrict__ bsum, int n) {
  int i = blockIdx.x * 256 + threadIdx.x;
  if (i < n) cur[i] += bsum[i >> 10];
}

// ---- XCD-partitioned bucketing: replica q = blockIdx&7 handles dst range
// [q*RNG, (q+1)*RNG). All csr writes of one range come from one XCD
// (under round-robin blockIdx->XCD), so lines write-combine in its L2.
// Correct under ANY mapping: ranges + cursor entries are disjoint per q.
__global__ __launch_bounds__(256) void reorder_xcd(const int* __restrict__ row,
    const int* __restrict__ col, const float* __restrict__ dinv,
    int* __restrict__ cursor, int2* __restrict__ csr, int e) {
  int q = blockIdx.x & (NXCD - 1);
  int chunk = blockIdx.x >> 3;
  int lo = q * RNG, hi = lo + RNG;
  int base = chunk * (256 * EPB) + threadIdx.x;
  #pragma unroll
  for (int it = 0; it < EPB; ++it) {
    int i = base + it * 256;
    if (i < e) {
      int c = col[i];
      if (c >= lo && c < hi) {
        int r = row[i];
        int pos = atomicAdd(&cursor[c], 1);
        csr[pos] = make_int2(r, __float_as_int(dinv[r] * dinv[c]));
      }
    }
  }
}

// g1 = glob_init @ w + b   (64 threads)
__global__ void glob1_kernel(const float* __restrict__ gi, const float* __restrict__ w,
                             const float* __restrict__ b, float* __restrict__ out) {
  int j = threadIdx.x;
  float acc = b[j];
  for (int k = 0; k < 64; ++k) acc += gi[k] * w[k * 64 + j];
  out[j] = acc;
}

// ---- gemm1: h1 = x @ w_nn1 + b_nn1 + g1, output bf16-packed [N][32] uints ----
__global__ __launch_bounds__(256) void gemm1(const float* __restrict__ x,
    const float* __restrict__ w, const float* __restrict__ b,
    const float* __restrict__ g1, uint* __restrict__ hbf, int n) {
  __shared__ float XsT[FIN][64];   // [k][r^swz] 32 KB
  __shared__ float Ws[FIN][DD];    // [k][j]     32 KB
  int base = blockIdx.x * 64;
  const float4* w4 = (const float4*)w;
  float4* ws4 = (float4*)Ws;
  for (int idx = threadIdx.x; idx < FIN * DD / 4; idx += 256) ws4[idx] = w4[idx];
  const float4* x4 = (const float4*)x;
  for (int idx = threadIdx.x; idx < 64 * FIN / 4; idx += 256) {
    int kq = idx & 31, r = idx >> 5;
    int gr = base + r;
    float4 v = make_float4(0.f, 0.f, 0.f, 0.f);
    if (gr < n) v = x4[gr * 32 + kq];
    int k0 = kq * 4, s = k0 & 60;
    XsT[k0 + 0][r ^ s] = v.x;
    XsT[k0 + 1][r ^ s] = v.y;
    XsT[k0 + 2][r ^ s] = v.z;
    XsT[k0 + 3][r ^ s] = v.w;
  }
  __syncthreads();
  int tx = threadIdx.x & 15, ty = threadIdx.x >> 4;
  float acc[4][4] = {};
  #pragma unroll 4
  for (int k = 0; k < FIN; ++k) {
    float4 av = *(const float4*)&XsT[k][(4 * ty) ^ (k & 60)];
    float4 bv = *(const float4*)&Ws[k][4 * tx];
    float ax[4] = {av.x, av.y, av.z, av.w};
    float bx[4] = {bv.x, bv.y, bv.z, bv.w};
    #pragma unroll
    for (int i = 0; i < 4; ++i)
      #pragma unroll
      for (int j = 0; j < 4; ++j)
        acc[i][j] += ax[i] * bx[j];
  }
  float bias[4];
  #pragma unroll
  for (int j = 0; j < 4; ++j) bias[j] = b[4 * tx + j] + g1[4 * tx + j];
  #pragma unroll
  for (int i = 0; i < 4; ++i) {
    int row = base + 4 * ty + i;
    if (row < n) {
      hbf[row * 32 + 2 * tx]     = packbf(acc[i][0] + bias[0], acc[i][1] + bias[1]);
      hbf[row * 32 + 2 * tx + 1] = packbf(acc[i][2] + bias[2], acc[i][3] + bias[3]);
    }
  }
}

// ---- gemm2: h2 = relu(hin) @ w_nn2 + b_nn2 + globs2[gidx], bf16 in/out ----
__global__ __launch_bounds__(256) void gemm2(const uint* __restrict__ hbf,
    const float* __restrict__ w, const float* __restrict__ bb,
    const float* __restrict__ globs2, const int* __restrict__ gidx,
    uint* __restrict__ obf, int n) {
  __shared__ float XsT[DD][64];    // 16 KB
  __shared__ float Ws[DD][DD];     // 16 KB
  int base = blockIdx.x * 64;
  const float4* w4 = (const float4*)w;
  float4* ws4 = (float4*)Ws;
  for (int idx = threadIdx.x; idx < DD * DD / 4; idx += 256) ws4[idx] = w4[idx];
  const uint2* h2 = (const uint2*)hbf;
  for (int idx = threadIdx.x; idx < 64 * DD / 4; idx += 256) {
    int kq = idx & 15, r = idx >> 4;
    int gr = base + r;
    uint2 v = make_uint2(0u, 0u);
    if (gr < n) v = h2[gr * 16 + kq];
    int k0 = kq * 4, s = k0 & 60;
    XsT[k0 + 0][r ^ s] = fmaxf(bflo(v.x), 0.f);
    XsT[k0 + 1][r ^ s] = fmaxf(bfhi(v.x), 0.f);
    XsT[k0 + 2][r ^ s] = fmaxf(bflo(v.y), 0.f);
    XsT[k0 + 3][r ^ s] = fmaxf(bfhi(v.y), 0.f);
  }
  __syncthreads();
  int tx = threadIdx.x & 15, ty = threadIdx.x >> 4;
  float acc[4][4] = {};
  #pragma unroll 4
  for (int k = 0; k < DD; ++k) {
    float4 av = *(const float4*)&XsT[k][(4 * ty) ^ (k & 60)];
    float4 bv = *(const float4*)&Ws[k][4 * tx];
    float ax[4] = {av.x, av.y, av.z, av.w};
    float bx[4] = {bv.x, bv.y, bv.z, bv.w};
    #pragma unroll
    for (int i = 0; i < 4; ++i)
      #pragma unroll
      for (int j = 0; j < 4; ++j)
        acc[i][j] += ax[i] * bx[j];
  }
  #pragma unroll
  for (int i = 0; i < 4; ++i) {
    int row = base + 4 * ty + i;
    if (row < n) {
      const float* gl = globs2 + gidx[row] * 64 + 4 * tx;
      float c0 = acc[i][0] + bb[4 * tx + 0] + gl[0];
      float c1 = acc[i][1] + bb[4 * tx + 1] + gl[1];
      float c2 = acc[i][2] + bb[4 * tx + 2] + gl[2];
      float c3 = acc[i][3] + bb[4 * tx + 3] + gl[3];
      obf[row * 32 + 2 * tx]     = packbf(c0, c1);
      obf[row * 32 + 2 * tx + 1] = packbf(c2, c3);
    }
  }
}

// ---- pull-gather: one wave per node, halves take even/odd edges, ILP 4.
// h is bf16-packed [N][32] uints; lane fp handles features 2fp, 2fp+1.
template <int SIG>
__global__ __launch_bounds__(256) void gather_agg(const int2* __restrict__ csr,
    const int* __restrict__ cursor, const int* __restrict__ deg,
    const float* __restrict__ dinv, const uint* __restrict__ h,
    void* __restrict__ outv, int n) {
  int node = blockIdx.x * 4 + (threadIdx.x >> 6);
  if (node >= n) return;
  int lane = threadIdx.x & 63;
  int half = lane >> 5, fp = lane & 31;
  int end = cursor[node];              // reorder advanced cursor to bucket end
  int start = end - deg[node];
  float a0 = 0.f, a1 = 0.f;
  int e = start + half;
  for (; e + 6 < end; e += 8) {        // 4 edges in flight per half
    int2 r0 = csr[e];
    int2 r1 = csr[e + 2];
    int2 r2 = csr[e + 4];
    int2 r3 = csr[e + 6];
    uint h0 = h[r0.x * 32 + fp];
    uint h1 = h[r1.x * 32 + fp];
    uint h2 = h[r2.x * 32 + fp];
    uint h3 = h[r3.x * 32 + fp];
    float w0 = __int_as_float(r0.y), w1 = __int_as_float(r1.y);
    float w2 = __int_as_float(r2.y), w3 = __int_as_float(r3.y);
    a0 += w0 * bflo(h0) + w1 * bflo(h1) + w2 * bflo(h2) + w3 * bflo(h3);
    a1 += w0 * bfhi(h0) + w1 * bfhi(h1) + w2 * bfhi(h2) + w3 * bfhi(h3);
  }
  for (; e < end; e += 2) {
    int2 r0 = csr[e];
    uint h0 = h[r0.x * 32 + fp];
    float w0 = __int_as_float(r0.y);
    a0 += w0 * bflo(h0);
    a1 += w0 * bfhi(h0);
  }
  if (half == 0) {                     // self-loop term, counted once
    float di = dinv[node], sc = di * di;
    uint hv = h[node * 32 + fp];
    a0 += sc * bflo(hv);
    a1 += sc * bfhi(hv);
  }
  a0 += __shfl(a0, lane ^ 32);
  a1 += __shfl(a1, lane ^ 32);
  if (half == 0) {
    if (SIG) {
      float2 o;
      o.x = 1.f / (1.f + __expf(-a0));
      o.y = 1.f / (1.f + __expf(-a1));
      ((float2*)outv)[node * 32 + fp] = o;
    } else {
      ((uint*)outv)[node * 32 + fp] = packbf(a0, a1);
    }
  }
}

// chunked segment-max over sorted graph_indices; bf16 input
__global__ void seg_max(const ushort* __restrict__ B, const int* __restrict__ gidx,
                        unsigned* __restrict__ parts_ord, int n, int chunk) {
  int f = threadIdx.x;
  int start = blockIdx.x * chunk;
  int end = start + chunk; if (end > n) end = n;
  if (start >= end) return;
  int curg = gidx[start];
  float m = -INFINITY;
  for (int i = start; i < end; ++i) {
    int g = gidx[i];
    if (g != curg) {
      atomicMax(&parts_ord[curg * 64 + f], f2ord(m));
      curg = g; m = -INFINITY;
    }
    m = fmaxf(m, __uint_as_float(((uint)B[i * 64 + f]) << 16));
  }
  atomicMax(&parts_ord[curg * 64 + f], f2ord(m));
}

// globs2[g] = ((glob_init@w_gg1 + b_gg1 + parts[g]@w_ng1 + b_ng1) @ w_gn2 + b_gn2)
__global__ void glob2_kernel(const float* __restrict__ gi, const unsigned* __restrict__ parts_ord,
    const float* __restrict__ w_gg1, const float* __restrict__ b_gg1,
    const float* __restrict__ w_ng1, const float* __restrict__ b_ng1,
    const float* __restrict__ w_gn2, const float* __restrict__ b_gn2,
    float* __restrict__ globs2) {
  __shared__ float t[64];
  int g = blockIdx.x, j = threadIdx.x;
  float acc = b_gg1[j] + b_ng1[j];
  for (int k = 0; k < 64; ++k) acc += gi[k] * w_gg1[k * 64 + j];
  for (int k = 0; k < 64; ++k) acc += ord2f(parts_ord[g * 64 + k]) * w_ng1[k * 64 + j];
  t[j] = acc;
  __syncthreads();
  float acc2 = b_gn2[j];
  for (int k = 0; k < 64; ++k) acc2 += t[k] * w_gn2[k * 64 + j];
  globs2[g * 64 + j] = acc2;
}

extern "C" void kernel_launch(void* const* d_in, const int* in_sizes, int n_in,
                              void* d_out, int out_size, void* d_ws, size_t ws_size,
                              hipStream_t stream) {
  const float* x         = (const float*)d_in[0];
  const int*   ei        = (const int*)d_in[1];
  const int*   gidx      = (const int*)d_in[2];
  const float* glob_init = (const float*)d_in[3];
  const float* w_nn1 = (const float*)d_in[4];  const float* b_nn1 = (const float*)d_in[5];
  const float* w_gn1 = (const float*)d_in[6];  const float* b_gn1 = (const float*)d_in[7];
  const float* w_gg1 = (const float*)d_in[8];  const float* b_gg1 = (const float*)d_in[9];
  const float* w_ng1 = (const float*)d_in[10]; const float* b_ng1 = (const float*)d_in[11];
  const float* w_nn2 = (const float*)d_in[12]; const float* b_nn2 = (const float*)d_in[13];
  const float* w_gn2 = (const float*)d_in[14]; const float* b_gn2 = (const float*)d_in[15];
  // w_gg2/b_gg2/w_ng2/b_ng2 are dead: layer-2 glob output is discarded.

  const int* row = ei;           // edge_index[0]
  const int* col = ei + EE;      // edge_index[1]

  // ---- workspace layout (256-aligned) ----
  char* p = (char*)d_ws;
  int*      deg    = (int*)p;       p += ((NN * 4 + 255) & ~255);
  float*    dinv   = (float*)p;     p += ((NN * 4 + 255) & ~255);
  int*      cursor = (int*)p;       p += ((NN * 4 + 255) & ~255);
  int*      bsum   = (int*)p;       p += 1024;
  int2*     csr    = (int2*)p;      p += (size_t)EE * 8;
  uint*     A      = (uint*)p;      p += (size_t)NN * 32 * 4;   // bf16 h buffer [N][32] uints
  unsigned* parts  = (unsigned*)p;  p += NG * 64 * 4;
  float*    g1     = (float*)p;     p += 256;
  float*    globs2 = (float*)p;
  uint*     B      = (uint*)d_out;  // bf16 agg1 buffer lives in d_out (fully overwritten later)
  float*    out    = (float*)d_out;

  const int NB = (NN + 1023) / 1024;
  const int NCHUNK = (EE + 256 * EPB - 1) / (256 * EPB);

  // ---- CSC build (shared by both layers) ----
  hipMemsetAsync(deg, 0, NN * 4, stream);
  count_deg<<<(EE + 255) / 256, 256, 0, stream>>>(col, deg, EE);
  deg_to_dinv<<<(NN + 255) / 256, 256, 0, stream>>>(deg, dinv, NN);
  scan1<<<NB, 1024, 0, stream>>>(deg, cursor, bsum, NN);
  scan2<<<1, 64, 0, stream>>>(bsum, NB);
  scan3<<<(NN + 255) / 256, 256, 0, stream>>>(cursor, bsum, NN);
  reorder_xcd<<<NXCD * NCHUNK, 256, 0, stream>>>(row, col, dinv, cursor, csr, EE);

  // ---- layer 1 ----
  glob1_kernel<<<1, 64, 0, stream>>>(glob_init, w_gn1, b_gn1, g1);
  gemm1<<<(NN + 63) / 64, 256, 0, stream>>>(x, w_nn1, b_nn1, g1, A, NN);
  gather_agg<0><<<(NN + 3) / 4, 256, 0, stream>>>(csr, cursor, deg, dinv, A, (void*)B, NN);

  // readout -> per-graph globals for layer 2
  hipMemsetAsync(parts, 0, NG * 64 * 4, stream);
  seg_max<<<(NN + 63) / 64, 64, 0, stream>>>((const ushort*)B, gidx, parts, NN, 64);
  glob2_kernel<<<NG, 64, 0, stream>>>(glob_init, parts, w_gg1, b_gg1, w_ng1, b_ng1,
                                      w_gn2, b_gn2, globs2);

  // ---- layer 2 (glob output discarded by reference) ----
  gemm2<<<(NN + 63) / 64, 256, 0, stream>>>(B, w_nn2, b_nn2, globs2, gidx, A, NN);
  gather_agg<1><<<(NN + 3) / 4, 256, 0, stream>>>(csr, cursor, deg, dinv, A, (void*)out, NN);
}